// Round 1
// baseline (4478.628 us; speedup 1.0000x reference)
//
#include <hip/hip_runtime.h>
#include <hip/hip_bf16.h>

#define C_DIM 2048
#define H_DIM 48
#define W_DIM 96
#define N_DIM 4
#define HW    (H_DIM * W_DIM)   /* 4608 */
#define NJ    (N_DIM * W_DIM)   /* 384 columns (n,w) */
#define KH_MID 4

typedef __bf16 bf16x8 __attribute__((ext_vector_type(8)));
typedef float  floatx4 __attribute__((ext_vector_type(4)));

// Pack middle tap W[:,:,4,0] -> bf16 row-major [o][c]
__global__ void pack_w(const float* __restrict__ W, __hip_bfloat16* __restrict__ Wbf) {
    int i = blockIdx.x * blockDim.x + threadIdx.x;   // i = o*C + c
    Wbf[i] = __float2bfloat16(W[i * 9 + KH_MID]);
}

// down[0] = fea[:,:,0,:]; also pack carry0[j][c] bf16 (j = n*W + w)
__global__ void init_carry(const float* __restrict__ fea, float* __restrict__ out,
                           __hip_bfloat16* __restrict__ carry0) {
    int i = blockIdx.x * blockDim.x + threadIdx.x;   // over N*C*W
    int w  = i % W_DIM;
    int nc = i / W_DIM;            // n*C + c
    int c  = nc % C_DIM;
    int n  = nc / C_DIM;
    float v = fea[(size_t)nc * HW + w];   // h = 0
    out[(size_t)nc * HW + w] = v;
    carry0[(n * W_DIM + w) * C_DIM + c] = __float2bfloat16(v);
}

// One recurrence step:
//   new[o][j] = relu( sum_c Wm[o][c]*carry[c][j] + b[o] ) + residual[n][o][h][w]
// MFMA orientation: M=j (rows), N=o (cols), K=c.
//   A[m][k] = carry_p[j=m][c=k]   (carry packed [j][c], contiguous in c)
//   B[k][n] = Wbf[o=n][c=k]       (row-major, contiguous in c)
// Block: 256 thr = 4 waves; tile 64j x 64o; wave wv owns 16j x 64o.
__global__ void step_kernel(const __hip_bfloat16* __restrict__ Wbf,
                            const __hip_bfloat16* __restrict__ carry_src,
                            __hip_bfloat16* __restrict__ carry_dst,
                            const float* __restrict__ bias,
                            const float* __restrict__ residual,
                            float* __restrict__ outp,
                            int h) {
    const int o0   = blockIdx.x * 64;
    const int j0   = blockIdx.y * 64;
    const int tid  = threadIdx.x;
    const int wv   = tid >> 6;
    const int lane = tid & 63;
    const int col16 = lane & 15;
    const int q     = lane >> 4;
    const int jw = j0 + wv * 16;

    floatx4 acc[4];
    #pragma unroll
    for (int t = 0; t < 4; ++t) acc[t] = (floatx4){0.f, 0.f, 0.f, 0.f};

    // fragment base pointers (element offsets are multiples of 8 -> 16B aligned)
    const bf16x8* ap  = (const bf16x8*)(carry_src + (size_t)(jw + col16) * C_DIM + q * 8);
    const bf16x8* bp0 = (const bf16x8*)(Wbf + (size_t)(o0 +  0 + col16) * C_DIM + q * 8);
    const bf16x8* bp1 = (const bf16x8*)(Wbf + (size_t)(o0 + 16 + col16) * C_DIM + q * 8);
    const bf16x8* bp2 = (const bf16x8*)(Wbf + (size_t)(o0 + 32 + col16) * C_DIM + q * 8);
    const bf16x8* bp3 = (const bf16x8*)(Wbf + (size_t)(o0 + 48 + col16) * C_DIM + q * 8);

    #pragma unroll 4
    for (int k = 0; k < C_DIM / 32; ++k) {
        bf16x8 a  = ap[k * 4];          // advance 32 channels per k
        bf16x8 b0 = bp0[k * 4];
        bf16x8 b1 = bp1[k * 4];
        bf16x8 b2 = bp2[k * 4];
        bf16x8 b3 = bp3[k * 4];
        acc[0] = __builtin_amdgcn_mfma_f32_16x16x32_bf16(a, b0, acc[0], 0, 0, 0);
        acc[1] = __builtin_amdgcn_mfma_f32_16x16x32_bf16(a, b1, acc[1], 0, 0, 0);
        acc[2] = __builtin_amdgcn_mfma_f32_16x16x32_bf16(a, b2, acc[2], 0, 0, 0);
        acc[3] = __builtin_amdgcn_mfma_f32_16x16x32_bf16(a, b3, acc[3], 0, 0, 0);
    }

    // Epilogue. D layout: row(M=j) = q*4 + r, col(N=o) = col16.
    const int jb = jw + q * 4;
    #pragma unroll
    for (int t = 0; t < 4; ++t) {
        const int o = o0 + t * 16 + col16;
        const float bo = bias[o];
        #pragma unroll
        for (int r = 0; r < 4; ++r) {
            const int j = jb + r;
            const int n = j / W_DIM;
            const int w = j % W_DIM;
            float v = acc[t][r] + bo;
            v = fmaxf(v, 0.f);
            const size_t off = (size_t)(n * C_DIM + o) * HW + h * W_DIM + w;
            v += residual[off];
            outp[off] = v;
            carry_dst[j * C_DIM + o] = __float2bfloat16(v);
        }
    }
}

extern "C" void kernel_launch(void* const* d_in, const int* in_sizes, int n_in,
                              void* d_out, int out_size, void* d_ws, size_t ws_size,
                              hipStream_t stream) {
    const float* fea = (const float*)d_in[0];
    const float* W   = (const float*)d_in[1];
    const float* b   = (const float*)d_in[2];
    float* out = (float*)d_out;

    __hip_bfloat16* Wbf    = (__hip_bfloat16*)d_ws;                 // 8 MB
    __hip_bfloat16* carryA = Wbf + (size_t)C_DIM * C_DIM;           // 1.5 MB
    __hip_bfloat16* carryB = carryA + (size_t)NJ * C_DIM;           // 1.5 MB
    __hip_bfloat16* bufs[2] = {carryA, carryB};

    hipLaunchKernelGGL(pack_w, dim3((C_DIM * C_DIM) / 256), dim3(256), 0, stream, W, Wbf);
    hipLaunchKernelGGL(init_carry, dim3((N_DIM * C_DIM * W_DIM) / 256), dim3(256), 0, stream,
                       fea, out, carryA);

    int cur = 0;
    // Pass 1: down[h] = relu(Wm@down[h-1]+b) + fea[:,:,h,:], h = 1..47
    for (int h = 1; h < H_DIM; ++h) {
        hipLaunchKernelGGL(step_kernel, dim3(C_DIM / 64, NJ / 64), dim3(256), 0, stream,
                           Wbf, bufs[cur], bufs[cur ^ 1], b, fea, out, h);
        cur ^= 1;
    }
    // Pass 2 (reverse): stack[h] = relu(Wm@carry+b) + down[h], h = 46..0 (in place in d_out)
    for (int h = H_DIM - 2; h >= 0; --h) {
        hipLaunchKernelGGL(step_kernel, dim3(C_DIM / 64, NJ / 64), dim3(256), 0, stream,
                           Wbf, bufs[cur], bufs[cur ^ 1], b, out, out, h);
        cur ^= 1;
    }
}

// Round 2
// 3132.494 us; speedup vs baseline: 1.4297x; 1.4297x over previous
//
#include <hip/hip_runtime.h>
#include <hip/hip_bf16.h>

#define C_DIM 2048
#define H_DIM 48
#define W_DIM 96
#define N_DIM 4
#define HW    (H_DIM * W_DIM)   /* 4608 */
#define NJ    (N_DIM * W_DIM)   /* 384 columns (n,w) */
#define KH_MID 4

#define BO 64                 /* o-rows per block  */
#define BJ 48                 /* j-rows per block  */
#define KC 256                /* K chunk           */
#define NCHUNK (C_DIM / KC)   /* 8                 */
#define NWAVES 12
#define NTHREADS 768
#define NSEG 32               /* 64*256/8 granules / 64 lanes */

typedef __bf16 bf16x8 __attribute__((ext_vector_type(8)));
typedef float  floatx4 __attribute__((ext_vector_type(4)));

__device__ __forceinline__ void gload_lds16(const __hip_bfloat16* g, __hip_bfloat16* l) {
    __builtin_amdgcn_global_load_lds(
        (const __attribute__((address_space(1))) void*)g,
        (__attribute__((address_space(3))) void*)l, 16, 0, 0);
}

// Pack middle tap W[:,:,4,0] -> bf16 row-major [o][c]
__global__ void pack_w(const float* __restrict__ W, __hip_bfloat16* __restrict__ Wbf) {
    int i = blockIdx.x * blockDim.x + threadIdx.x;   // i = o*C + c
    Wbf[i] = __float2bfloat16(W[i * 9 + KH_MID]);
}

// down[0] = fea[:,:,0,:]; also pack carry0[j][c] bf16 (j = n*W + w)
__global__ void init_carry(const float* __restrict__ fea, float* __restrict__ out,
                           __hip_bfloat16* __restrict__ carry0) {
    int i = blockIdx.x * blockDim.x + threadIdx.x;   // over N*C*W
    int w  = i % W_DIM;
    int nc = i / W_DIM;            // n*C + c
    int c  = nc % C_DIM;
    int n  = nc / C_DIM;
    float v = fea[(size_t)nc * HW + w];   // h = 0
    out[(size_t)nc * HW + w] = v;
    carry0[(n * W_DIM + w) * C_DIM + c] = __float2bfloat16(v);
}

// One recurrence step, LDS-staged GEMM.
//   new[o][j] = relu( sum_c Wm[o][c]*carry[j][c] + b[o] ) + residual[n][o][h][w]
// MFMA 16x16x32, M=j, N=o, K=c.
// Block: 768 thr = 12 waves = (4 ot) x (3 jt); tile 64o x 48j; grid 256 (= 1/CU).
// W chunk (64o x 256c) staged in 32KB LDS via global_load_lds (granule order =
// exactly the read order -> conflict-free linear ds_read_b128).
// A (carry) read per-lane 16B from global; 1.5MB carry is L2/L1-resident.
__global__ __launch_bounds__(NTHREADS, 1) void step_kernel(
    const __hip_bfloat16* __restrict__ Wbf,
    const __hip_bfloat16* __restrict__ carry_src,
    __hip_bfloat16* __restrict__ carry_dst,
    const float* __restrict__ bias,
    const float* __restrict__ residual,
    float* __restrict__ outp, int h)
{
    __shared__ __hip_bfloat16 Bsh[BO * KC];   // 32 KB

    const int id = blockIdx.x;
    const int og = id & 31;          // og % 8 -> XCD: each XCD keeps a 1MB W-slice in L2
    const int jg = id >> 5;          // 8 j-groups
    const int o0 = og * BO;
    const int j0 = jg * BJ;

    const int tid  = threadIdx.x;
    const int wv   = tid >> 6;
    const int lane = tid & 63;
    const int c16  = lane & 15;
    const int q    = lane >> 4;
    const int ot   = wv & 3;         // 0..3
    const int jt   = wv >> 2;        // 0..2

    floatx4 acc = {0.f, 0.f, 0.f, 0.f};

    // A-fragment per-lane global base: row j0+jt*16+c16, col q*8
    const __hip_bfloat16* aptr = carry_src + (size_t)(j0 + jt * 16 + c16) * C_DIM + q * 8;
    // B read slot within a k-iter: granule = kk*256 + (ot*16+c16)*4 + q
    const int b_slot = (ot * 16 + c16) * 4 + q;

    for (int ch = 0; ch < NCHUNK; ++ch) {
        // ---- stage W chunk: 2048 granules of 16B, 32 wave-segments ----
        for (int s = wv; s < NSEG; s += NWAVES) {
            const int g  = s * 64 + lane;      // linear granule id == LDS slot
            const int kk = g >> 8;             // 0..7
            const int r  = (g >> 2) & 63;      // o-row 0..63
            const int qq = g & 3;              // 16B sub-granule in 32c group
            const __hip_bfloat16* gsrc =
                Wbf + (size_t)(o0 + r) * C_DIM + ch * KC + kk * 32 + qq * 8;
            gload_lds16(gsrc, Bsh + (size_t)s * 512);   // dest = base + lane*16
        }
        __syncthreads();

        const __hip_bfloat16* ap = aptr + ch * KC;
        const bf16x8* bbase = (const bf16x8*)Bsh;
        #pragma unroll
        for (int kk = 0; kk < KC / 32; ++kk) {
            bf16x8 a = *(const bf16x8*)(ap + kk * 32);
            bf16x8 b = bbase[kk * 256 + b_slot];
            acc = __builtin_amdgcn_mfma_f32_16x16x32_bf16(a, b, acc, 0, 0, 0);
        }
        __syncthreads();
    }

    // ---- epilogue: D row(M=j) = q*4 + r, col(N=o) = c16 ----
    const int o  = o0 + ot * 16 + c16;
    const float bo = bias[o];
    const int jb = j0 + jt * 16 + q * 4;
    #pragma unroll
    for (int r = 0; r < 4; ++r) {
        const int j = jb + r;
        const int n = j / W_DIM;
        const int w = j % W_DIM;
        float v = fmaxf(acc[r] + bo, 0.f);
        const size_t off = (size_t)(n * C_DIM + o) * HW + h * W_DIM + w;
        v += residual[off];
        outp[off] = v;
        carry_dst[j * C_DIM + o] = __float2bfloat16(v);
    }
}

extern "C" void kernel_launch(void* const* d_in, const int* in_sizes, int n_in,
                              void* d_out, int out_size, void* d_ws, size_t ws_size,
                              hipStream_t stream) {
    const float* fea = (const float*)d_in[0];
    const float* W   = (const float*)d_in[1];
    const float* b   = (const float*)d_in[2];
    float* out = (float*)d_out;

    __hip_bfloat16* Wbf    = (__hip_bfloat16*)d_ws;                 // 8 MB
    __hip_bfloat16* carryA = Wbf + (size_t)C_DIM * C_DIM;           // 1.5 MB
    __hip_bfloat16* carryB = carryA + (size_t)NJ * C_DIM;           // 1.5 MB
    __hip_bfloat16* bufs[2] = {carryA, carryB};

    hipLaunchKernelGGL(pack_w, dim3((C_DIM * C_DIM) / 256), dim3(256), 0, stream, W, Wbf);
    hipLaunchKernelGGL(init_carry, dim3((N_DIM * C_DIM * W_DIM) / 256), dim3(256), 0, stream,
                       fea, out, carryA);

    int cur = 0;
    // Pass 1: down[h] = relu(Wm@down[h-1]+b) + fea[:,:,h,:], h = 1..47
    for (int h = 1; h < H_DIM; ++h) {
        hipLaunchKernelGGL(step_kernel, dim3(256), dim3(NTHREADS), 0, stream,
                           Wbf, bufs[cur], bufs[cur ^ 1], b, fea, out, h);
        cur ^= 1;
    }
    // Pass 2 (reverse): stack[h] = relu(Wm@carry+b) + down[h], h = 46..0 (in place)
    for (int h = H_DIM - 2; h >= 0; --h) {
        hipLaunchKernelGGL(step_kernel, dim3(256), dim3(NTHREADS), 0, stream,
                           Wbf, bufs[cur], bufs[cur ^ 1], b, out, out, h);
        cur ^= 1;
    }
}